// Round 2
// baseline (1344.095 us; speedup 1.0000x reference)
//
#include <hip/hip_runtime.h>
#include <stdint.h>

#define Bb   16
#define INn  8192
#define Cc   64
#define Aa   512
#define Nn   512
#define OUTo 1024
#define Tt   32

// ---------------------------------------------------------------------------
// Spike schedule per (b, i) as a 32-bit mask (bit t = spike at cycle t).
// fp32 ops replicate the numpy reference exactly (rintf = round-half-even,
// fmodf exact for positive args, fp32 division).
// ---------------------------------------------------------------------------
__global__ void spike_kernel(const float* __restrict__ x,
                             uint32_t* __restrict__ spk) {
    int idx = blockIdx.x * 256 + threadIdx.x;
    if (idx >= Bb * INn) return;
    float xv = x[idx];
    float nf = rintf(xv * 32.0f);
    int nspk = (int)nf;
    uint32_t m;
    if (nspk >= 32) {
        m = 0xFFFFFFFFu;
    } else if (nspk <= 0) {
        m = 0u;
    } else {
        float spacing = 32.0f / nf;
        m = 0u;
        #pragma unroll
        for (int t = 0; t < 32; ++t) {
            float ct = (float)t;
            bool fire = (floorf(ct / spacing) < nf) &&
                        (floorf(fmodf(ct, spacing)) == 0.0f);
            if (fire) m |= (1u << t);
        }
    }
    spk[idx] = m;
}

// ---------------------------------------------------------------------------
// Per-cycle signal gather: sig[c][a][b] = 0.0f / 1.0f.
// Wide grid (2048 blocks); random 4B loads from spk (512 KB) / buf (2 MB),
// both L2/L3 resident; writes fully coalesced.
// ---------------------------------------------------------------------------
__global__ void gather_kernel(const int* __restrict__ src_core,
                              const int* __restrict__ src_index,
                              const uint32_t* __restrict__ spk,
                              const uint32_t* __restrict__ buf,
                              float* __restrict__ sig, int t) {
    int idx = blockIdx.x * 256 + threadIdx.x;    // over C*A*16
    int b  = idx & 15;
    int ca = idx >> 4;                           // c*512 + a
    int sc = src_core[ca];
    int si = src_index[ca];
    float v;
    if (sc < 0) {
        v = (float)((spk[b * INn + si] >> t) & 1u);
    } else {
        v = (t > 0) ? (float)((buf[(sc * Bb + b) * Nn + si] >> (t - 1)) & 1u)
                    : 0.0f;
    }
    sig[ca * 16 + b] = v;
}

// ---------------------------------------------------------------------------
// One simulation cycle (GEMM + fire). Grid (64, 8), 128-thread blocks.
// Wave 0 of a block handles batches 0-7, wave 1 batches 8-15 (bh is
// wave-uniform; readfirstlane forces the compiler to treat it as scalar).
// Thread owns one n row (W row exclusive within wave; the twin wave reuses
// the same row via L1). Signals are wave-uniform -> scalar s_load path
// (no LDS at all). Accumulation is sequential over a, products are exact
// (sig in {0.0,1.0}) => bit-identical to the validated round-1 arithmetic.
// ---------------------------------------------------------------------------
__global__ __launch_bounds__(128) void cycle_kernel(
        const float* __restrict__ W,
        const float* __restrict__ thr,
        const float* __restrict__ sig,
        uint32_t* __restrict__ buf,
        float* __restrict__ memb,
        int t) {
    const int c  = blockIdx.x;
    const int bh = __builtin_amdgcn_readfirstlane(threadIdx.x >> 6); // 0 or 1
    const int n  = blockIdx.y * 64 + (threadIdx.x & 63);

    const float* __restrict__ wrow = W + (size_t)(c * Nn + n) * Aa;
    const float* __restrict__ sgc  = sig + c * Aa * 16 + bh * 8;

    float acc[8];
    #pragma unroll
    for (int j = 0; j < 8; ++j) acc[j] = 0.0f;

    for (int a0 = 0; a0 < Aa; a0 += 4) {
        float4 w4 = *(const float4*)(wrow + a0);
        #pragma unroll
        for (int k = 0; k < 4; ++k) {
            float w = (k == 0) ? w4.x : (k == 1) ? w4.y : (k == 2) ? w4.z : w4.w;
            const float* sa = sgc + (size_t)(a0 + k) * 16;   // wave-uniform
            acc[0] += w * sa[0];
            acc[1] += w * sa[1];
            acc[2] += w * sa[2];
            acc[3] += w * sa[3];
            acc[4] += w * sa[4];
            acc[5] += w * sa[5];
            acc[6] += w * sa[6];
            acc[7] += w * sa[7];
        }
    }

    const float th = thr[c];
    #pragma unroll
    for (int j = 0; j < 8; ++j) {
        int b = bh * 8 + j;
        size_t off = (size_t)(c * Bb + b) * Nn + n;
        float m = memb[off] + acc[j];      // single add, like reference
        uint32_t wd = buf[off];
        if (th < m) {                       // strict <, like reference
            m -= th;
            wd |= (1u << t);
        }
        memb[off] = m;
        buf[off] = wd;
    }
}

// ---------------------------------------------------------------------------
// out[b, o] = popcount(buf[oc[o], b, oi[o]]).
// ---------------------------------------------------------------------------
__global__ void out_kernel(const uint32_t* __restrict__ buf,
                           const int* __restrict__ oc,
                           const int* __restrict__ oi,
                           float* __restrict__ out) {
    int idx = blockIdx.x * 256 + threadIdx.x;
    if (idx >= Bb * OUTo) return;
    int b = idx / OUTo;
    int o = idx - b * OUTo;
    uint32_t wd = buf[(oc[o] * Bb + b) * Nn + oi[o]];
    out[idx] = (float)__popc(wd);
}

extern "C" void kernel_launch(void* const* d_in, const int* in_sizes, int n_in,
                              void* d_out, int out_size, void* d_ws,
                              size_t ws_size, hipStream_t stream) {
    const float* x         = (const float*)d_in[0];
    const float* W         = (const float*)d_in[1];
    const float* thr       = (const float*)d_in[2];
    const int*   src_core  = (const int*)d_in[3];
    const int*   src_index = (const int*)d_in[4];
    const int*   osc       = (const int*)d_in[5];
    const int*   osi       = (const int*)d_in[6];
    float* out = (float*)d_out;

    // ws layout: spk [B*IN u32] | buf [C*B*N u32] | memb [C*B*N f32] | sig [C*A*16 f32]
    char* p = (char*)d_ws;
    uint32_t* spk  = (uint32_t*)p;                 p += (size_t)Bb * INn * 4;
    uint32_t* buf  = (uint32_t*)p;                 p += (size_t)Cc * Bb * Nn * 4;
    float*    memb = (float*)p;                    p += (size_t)Cc * Bb * Nn * 4;
    float*    sig  = (float*)p;

    // zero buf + memb each call (they are adjacent)
    hipMemsetAsync(buf, 0, (size_t)Cc * Bb * Nn * 4 * 2, stream);

    spike_kernel<<<dim3((Bb * INn) / 256), 256, 0, stream>>>(x, spk);

    for (int t = 0; t < Tt; ++t) {
        gather_kernel<<<dim3((Cc * Aa * Bb) / 256), 256, 0, stream>>>(
            src_core, src_index, spk, buf, sig, t);
        cycle_kernel<<<dim3(Cc, 8), 128, 0, stream>>>(
            W, thr, sig, buf, memb, t);
    }

    out_kernel<<<dim3((Bb * OUTo + 255) / 256), 256, 0, stream>>>(
        buf, osc, osi, out);
}